// Round 7
// baseline (718.660 us; speedup 1.0000x reference)
//
#include <hip/hip_runtime.h>

// TransformerDecoderLayerQaN — MI355X round 7.
// gemm2: BK=64 frag-order global_load_lds GEMM, BN=64 grids (2x blocks).
// attn_v3: wave-private flash attn, K reg-prefetch + frag-order LDS,
// V frags gathered directly from L2 (no transpose, no V LDS).
//
// ws layout (total 61,689,856 B):
//   QA scratch: qeff@0, p@20480, Acomb@675840, mixed@872448 (dead after ln_qa)
//   y1   bf16 [T*B*D]    @ 2969600   (reused: fb = lin2 out)
//   qb   bf16 [T*B*D]    @ 19746816  (reused: t1 = out_proj out; hb = FFN hidden)
//   kvb  bf16 [S*B][1024]@ 36524032  (K cols 0..511, V cols 512..1023)
//     post-attn: opwb@36524032, l1wb@37048320, l2wb@39145472
//   ob   bf16 [T*B*D]    @ 44912640  (reused: y2 = LN2 out)
//     pre-attn: ipwb@44912640, memb@46485504

typedef unsigned short u16;
typedef unsigned int u32;
typedef short short8_t __attribute__((ext_vector_type(8)));
typedef float f32x4 __attribute__((ext_vector_type(4)));

#define TT 2048
#define BB 8
#define SS 512
#define DD 512
#define HH 8
#define DH 64
#define DFF 2048
#define NQ 10
#define WW 16
#define NW 128
#define KVS 1024

__device__ __forceinline__ float b2f(u16 u) {
    return __uint_as_float(((unsigned int)u) << 16);
}
__device__ __forceinline__ u16 f2b(float f) {
    unsigned int x = __float_as_uint(f);
    unsigned int r = x + 0x7FFFu + ((x >> 16) & 1u);
    return (u16)(r >> 16);
}
__device__ __forceinline__ float wave_sum(float v) {
    #pragma unroll
    for (int o = 32; o > 0; o >>= 1) v += __shfl_xor(v, o, 64);
    return v;
}
__device__ __forceinline__ float wave_max(float v) {
    #pragma unroll
    for (int o = 32; o > 0; o >>= 1) v = fmaxf(v, __shfl_xor(v, o, 64));
    return v;
}
__device__ __forceinline__ void load4(const u16* p, float* v) {
    ushort4 t = *(const ushort4*)p;
    v[0] = b2f(t.x); v[1] = b2f(t.y); v[2] = b2f(t.z); v[3] = b2f(t.w);
}
__device__ __forceinline__ void load4(const float* p, float* v) {
    float4 t = *(const float4*)p;
    v[0] = t.x; v[1] = t.y; v[2] = t.z; v[3] = t.w;
}
__device__ __forceinline__ void st1(u16* p, float v) { *p = f2b(v); }
__device__ __forceinline__ void st1(float* p, float v) { *p = v; }

__device__ __forceinline__ void async16(const u16* g, u16* l) {
    __builtin_amdgcn_global_load_lds((const __attribute__((address_space(1))) u32*)g,
                                     (__attribute__((address_space(3))) u32*)l, 16, 0, 0);
}

// ---------------- f32 -> bf16 convert ----------------
__global__ __launch_bounds__(256) void cvt_kernel(const float* __restrict__ src,
                                                  u16* __restrict__ dst) {
    int i = (blockIdx.x * 256 + threadIdx.x) * 4;
    float4 v = *(const float4*)(src + i);
    ushort4 o;
    o.x = f2b(v.x); o.y = f2b(v.y); o.z = f2b(v.z); o.w = f2b(v.w);
    *(ushort4*)(dst + i) = o;
}

// ---------------- QA block (R2 verbatim) ----------------
__global__ __launch_bounds__(512) void qeff_kernel(const float* __restrict__ queries,
                                                   float* __restrict__ qeff) {
    int d = threadIdx.x;
    const float KS = 0.0055242717280199026f; // 1/(8*sqrt(512))
    for (int n = 0; n < NQ; n++) {
        float v = queries[n * DD + d];
        float ss = wave_sum(v * v);
        float norm = sqrtf(ss);
        qeff[n * DD + d] = v / (norm + 1e-6f) * KS;
    }
}

__global__ __launch_bounds__(256) void p_kernel(const float* __restrict__ x,
                                                const float* __restrict__ qeff,
                                                float* __restrict__ p) {
    __shared__ float qe[NQ * DD];
    for (int i = threadIdx.x; i < NQ * DD; i += 256) qe[i] = qeff[i];
    __syncthreads();
    int b = blockIdx.x >> 9;
    int t = ((blockIdx.x & 511) << 2) + (threadIdx.x >> 6);
    int lane = threadIdx.x & 63;
    const float* xr = x + ((size_t)t * BB + b) * DD;
    float acc[NQ];
    #pragma unroll
    for (int n = 0; n < NQ; n++) acc[n] = 0.f;
    #pragma unroll
    for (int c = 0; c < 8; c++) {
        int d = c * 64 + lane;
        float xv = xr[d];
        #pragma unroll
        for (int n = 0; n < NQ; n++) acc[n] += xv * qe[n * DD + d];
    }
    #pragma unroll
    for (int n = 0; n < NQ; n++) {
        float s = wave_sum(acc[n]);
        if (lane == 0) p[((size_t)(b * NQ + n)) * TT + t] = s;
    }
}

__global__ __launch_bounds__(256) void win_kernel(const float* __restrict__ p,
                                                  const float* __restrict__ wk,
                                                  float* __restrict__ Acomb) {
    int id = blockIdx.x * 4 + (threadIdx.x >> 6); // b*NW + m
    int b = id >> 7, m = id & 127;
    int j = threadIdx.x & 63;
    int tj = (m - 1) * WW + j;
    bool valid = (j < 48) && (tj >= 0) && (tj < TT);
    float acc = 0.f;
    for (int n = 0; n < NQ; n++) {
        float v = valid ? p[((size_t)(b * NQ + n)) * TT + tj] : -1e30f;
        float mx = wave_max(v);
        float e = valid ? __expf(v - mx) : 0.f;
        float s = wave_sum(e);
        acc += wk[n] * (e / s);
    }
    if (j < 48) Acomb[(size_t)id * 48 + j] = acc;
}

__global__ __launch_bounds__(256) void mix_kernel(const float* __restrict__ Acomb,
                                                  const float* __restrict__ x,
                                                  float* __restrict__ mixed) {
    __shared__ float As[48];
    int id = blockIdx.x;
    int b = id >> 7, m = id & 127;
    if (threadIdx.x < 48) As[threadIdx.x] = Acomb[(size_t)id * 48 + threadIdx.x];
    __syncthreads();
    int d0 = threadIdx.x, d1 = threadIdx.x + 256;
    float a0 = 0.f, a1 = 0.f;
    int tb = (m - 1) * WW;
    for (int j = 0; j < 48; j++) {
        int t = tb + j;
        if ((unsigned)t < (unsigned)TT) {
            float aj = As[j];
            const float* xr = x + ((size_t)t * BB + b) * DD;
            a0 += aj * xr[d0];
            a1 += aj * xr[d1];
        }
    }
    mixed[(size_t)id * DD + d0] = a0;
    mixed[(size_t)id * DD + d1] = a1;
}

__global__ __launch_bounds__(256) void ln_qa_kernel(const float* __restrict__ a,
                                                    const float* __restrict__ mixed,
                                                    const float* __restrict__ g,
                                                    const float* __restrict__ bt,
                                                    u16* __restrict__ out) {
    int r = blockIdx.x * 4 + (threadIdx.x >> 6); // r = t*B+b
    int lane = threadIdx.x & 63;
    int t = r >> 3, b = r & 7;
    const float* ar = a + (size_t)r * DD;
    const float* mr = mixed + ((size_t)(b * NW + (t >> 4))) * DD;
    int d0 = lane * 8;
    float av[8], mv[8], gg[8], bb[8];
    load4(ar + d0, av); load4(ar + d0 + 4, av + 4);
    load4(mr + d0, mv); load4(mr + d0 + 4, mv + 4);
    load4(g + d0, gg);  load4(g + d0 + 4, gg + 4);
    load4(bt + d0, bb); load4(bt + d0 + 4, bb + 4);
    float v[8];
    float s = 0.f, s2 = 0.f;
    #pragma unroll
    for (int u = 0; u < 8; u++) { v[u] = av[u] + mv[u]; s += v[u]; s2 += v[u] * v[u]; }
    s = wave_sum(s); s2 = wave_sum(s2);
    float mu = s * (1.f / DD);
    float var = s2 * (1.f / DD) - mu * mu;
    float rs = rsqrtf(var + 1e-5f);
    #pragma unroll
    for (int u = 0; u < 8; u++) out[(size_t)r * DD + d0 + u] = f2b((v[u] - mu) * rs * gg[u] + bb[u]);
}

template <typename OT>
__global__ __launch_bounds__(256) void ln_rows_kernel(const u16* __restrict__ a,
                                                      const u16* __restrict__ bsrc,
                                                      const float* __restrict__ g,
                                                      const float* __restrict__ bt,
                                                      OT* __restrict__ out) {
    int r = blockIdx.x * 4 + (threadIdx.x >> 6);
    int lane = threadIdx.x & 63;
    const u16* ar = a + (size_t)r * DD;
    const u16* br = bsrc + (size_t)r * DD;
    int d0 = lane * 8;
    float av[8], cv[8], gg[8], bb[8];
    load4(ar + d0, av); load4(ar + d0 + 4, av + 4);
    load4(br + d0, cv); load4(br + d0 + 4, cv + 4);
    load4(g + d0, gg);  load4(g + d0 + 4, gg + 4);
    load4(bt + d0, bb); load4(bt + d0 + 4, bb + 4);
    float v[8];
    float s = 0.f, s2 = 0.f;
    #pragma unroll
    for (int u = 0; u < 8; u++) { v[u] = av[u] + cv[u]; s += v[u]; s2 += v[u] * v[u]; }
    s = wave_sum(s); s2 = wave_sum(s2);
    float mu = s * (1.f / DD);
    float var = s2 * (1.f / DD) - mu * mu;
    float rs = rsqrtf(var + 1e-5f);
    #pragma unroll
    for (int u = 0; u < 8; u++) st1(out + (size_t)r * DD + d0 + u, (v[u] - mu) * rs * gg[u] + bb[u]);
}

// ---------------- MFMA GEMM v2: BK=64, frag-order LDS, BN=64 ----------------
// C[M,N] = act(A[M,K] @ W[N,K]^T + bias). A,W bf16; C bf16; bias f32.
// 4 waves 2x2 over (WM x WN). Slot(g = mblk*2+kk, lane) holds 16B of
// row (g>>1)*16+n16, k kk*32+quad*8 -> all LDS traffic is b128 at
// base+lane*16 (conflict-free); DMA dest matches slot order.
template <int RELU, int BM, int BN, int WM, int WN>
__global__ __launch_bounds__(256) void gemm2(const u16* __restrict__ A,
                                             const u16* __restrict__ W,
                                             const float* __restrict__ bias,
                                             u16* __restrict__ C,
                                             int M, int N, int K) {
    constexpr int MT = WM / 16, NT = WN / 16;
    constexpr int GA = BM / 8, GB = BN / 8;   // 64-slot DMA groups
    constexpr int JA = GA / 4, JB = GB / 4;   // groups per wave
    __shared__ __align__(16) u16 As[BM * 64];
    __shared__ __align__(16) u16 Bs[BN * 64];
    int tid = threadIdx.x;
    int w = tid >> 6, lane = tid & 63;
    int n16 = lane & 15, quad = lane >> 4;
    int wm16 = (w >> 1) * MT, wn16 = (w & 1) * NT;
    int m0 = blockIdx.y * BM, n0 = blockIdx.x * BN;

    const u16* gA[JA]; u16* lA[JA];
    #pragma unroll
    for (int j = 0; j < JA; j++) {
        int g = w * JA + j;
        gA[j] = A + (size_t)(m0 + (g >> 1) * 16 + n16) * K + (g & 1) * 32 + quad * 8;
        lA[j] = As + (size_t)g * 512;
    }
    const u16* gB[JB]; u16* lB[JB];
    #pragma unroll
    for (int j = 0; j < JB; j++) {
        int g = w * JB + j;
        gB[j] = W + (size_t)(n0 + (g >> 1) * 16 + n16) * K + (g & 1) * 32 + quad * 8;
        lB[j] = Bs + (size_t)g * 512;
    }

    f32x4 acc[MT][NT];
    #pragma unroll
    for (int i = 0; i < MT; i++)
        #pragma unroll
        for (int j = 0; j < NT; j++) acc[i][j] = (f32x4){0.f, 0.f, 0.f, 0.f};

    for (int k0 = 0; k0 < K; k0 += 64) {
        __syncthreads();               // previous tile fully consumed
        #pragma unroll
        for (int j = 0; j < JA; j++) async16(gA[j] + k0, lA[j]);
        #pragma unroll
        for (int j = 0; j < JB; j++) async16(gB[j] + k0, lB[j]);
        __syncthreads();               // DMA drained
        short8_t af[MT][2], bf[NT][2];
        #pragma unroll
        for (int im = 0; im < MT; im++)
            #pragma unroll
            for (int kk = 0; kk < 2; kk++)
                af[im][kk] = *(const short8_t*)(As + (size_t)(((wm16 + im) * 2 + kk) * 64 + lane) * 8);
        #pragma unroll
        for (int in = 0; in < NT; in++)
            #pragma unroll
            for (int kk = 0; kk < 2; kk++)
                bf[in][kk] = *(const short8_t*)(Bs + (size_t)(((wn16 + in) * 2 + kk) * 64 + lane) * 8);
        #pragma unroll
        for (int kk = 0; kk < 2; kk++)
            #pragma unroll
            for (int im = 0; im < MT; im++)
                #pragma unroll
                for (int in = 0; in < NT; in++)
                    acc[im][in] = __builtin_amdgcn_mfma_f32_16x16x32_bf16(af[im][kk], bf[in][kk], acc[im][in], 0, 0, 0);
    }

    float bia[NT];
    #pragma unroll
    for (int in = 0; in < NT; in++) bia[in] = bias[n0 + (wn16 + in) * 16 + n16];
    #pragma unroll
    for (int im = 0; im < MT; im++) {
        #pragma unroll
        for (int r = 0; r < 4; r++) {
            int row = m0 + (wm16 + im) * 16 + quad * 4 + r;
            u16* crow = C + (size_t)row * N + n0 + wn16 * 16 + n16;
            #pragma unroll
            for (int in = 0; in < NT; in++) {
                float v = acc[im][in][r] + bia[in];
                if (RELU) v = fmaxf(v, 0.f);
                crow[in * 16] = f2b(v);
            }
        }
    }
}

// ---------------- MFMA flash attention v3 ----------------
// Wave-private (no barriers), fixed-max softmax (R6-proven). K staged in
// frag-order LDS with register prefetch of chunk c+1; V frags gathered
// directly from L2 (8 u16 per frag) — no transpose stores, no V LDS.
__global__ __launch_bounds__(256) void attn_v3(const u16* __restrict__ qb,
                                               const u16* __restrict__ kvb,
                                               u16* __restrict__ ob) {
    __shared__ __align__(16) u16 Kl[4][2048];  // 4KB/wave, frag-order slots
    __shared__ u16 Ps[4][16][40];
    int tid = threadIdx.x;
    int w = tid >> 6, lane = tid & 63;
    int n16 = lane & 15, quad = lane >> 4, q8 = quad * 8;
    int b = blockIdx.y >> 3, h = blockIdx.y & 7;
    int q0 = blockIdx.x * 64 + w * 16;

    const u16* qrow = qb + ((size_t)(q0 + n16) * BB + b) * DD + h * DH;
    short8_t aq0 = *(const short8_t*)(qrow + q8);
    short8_t aq1 = *(const short8_t*)(qrow + 32 + q8);

    const u16* kbase = kvb + (size_t)b * KVS + h * DH;
    const u16* vbase = kbase + 512;

    // K DMA-group source pointers: g -> key=(g>>1)*16+n16, d=(g&1)*32+quad*8
    const u16* kg[4];
    #pragma unroll
    for (int g = 0; g < 4; g++)
        kg[g] = kbase + (size_t)((g >> 1) * 16 + n16) * (BB * KVS) + (g & 1) * 32 + quad * 8;

    uint4 kr[4];
    #pragma unroll
    for (int g = 0; g < 4; g++) kr[g] = *(const uint4*)(kg[g]);

    float lsum[4];
    f32x4 Oa[4];
    #pragma unroll
    for (int r = 0; r < 4; r++) lsum[r] = 0.f;
    #pragma unroll
    for (int ot = 0; ot < 4; ot++) Oa[ot] = (f32x4){0.f, 0.f, 0.f, 0.f};

    for (int c = 0; c < 16; c++) {
        // store current K chunk (wave-private LDS, b128, conflict-free)
        #pragma unroll
        for (int g = 0; g < 4; g++)
            *(uint4*)&Kl[w][(g * 64 + lane) * 8] = kr[g];
        // prefetch next K chunk into registers (in flight during compute)
        if (c < 15) {
            #pragma unroll
            for (int g = 0; g < 4; g++)
                kr[g] = *(const uint4*)(kg[g] + (size_t)(c + 1) * 32 * (BB * KVS));
        }
        // V frag gathers (issue early; consumed after softmax)
        union { short8_t v; u16 e[8]; } vf[4];
        #pragma unroll
        for (int ot = 0; ot < 4; ot++)
            #pragma unroll
            for (int j = 0; j < 8; j++)
                vf[ot].e[j] = vbase[(size_t)(c * 32 + q8 + j) * (BB * KVS) + ot * 16 + n16];

        // scores S[16 q][32 keys]
        f32x4 sc[2];
        #pragma unroll
        for (int nt = 0; nt < 2; nt++) {
            short8_t bk0 = *(const short8_t*)&Kl[w][((nt * 2 + 0) * 64 + lane) * 8];
            short8_t bk1 = *(const short8_t*)&Kl[w][((nt * 2 + 1) * 64 + lane) * 8];
            f32x4 a = (f32x4){0.f, 0.f, 0.f, 0.f};
            a = __builtin_amdgcn_mfma_f32_16x16x32_bf16(aq0, bk0, a, 0, 0, 0);
            a = __builtin_amdgcn_mfma_f32_16x16x32_bf16(aq1, bk1, a, 0, 0, 0);
            sc[nt] = a;
        }

        // fixed-max softmax: p = exp(s/8 - 8)
        #pragma unroll
        for (int r = 0; r < 4; r++) {
            float p0 = __expf(sc[0][r] * 0.125f - 8.0f);
            float p1 = __expf(sc[1][r] * 0.125f - 8.0f);
            lsum[r] += p0 + p1;
            Ps[w][quad * 4 + r][n16] = f2b(p0);
            Ps[w][quad * 4 + r][16 + n16] = f2b(p1);
        }

        // O += P @ V
        short8_t ap = *(const short8_t*)&Ps[w][n16][q8];
        #pragma unroll
        for (int ot = 0; ot < 4; ot++)
            Oa[ot] = __builtin_amdgcn_mfma_f32_16x16x32_bf16(ap, vf[ot].v, Oa[ot], 0, 0, 0);
    }

    #pragma unroll
    for (int r = 0; r < 4; r++) {
        float l = lsum[r];
        #pragma unroll
        for (int o = 1; o < 16; o <<= 1) l += __shfl_xor(l, o, 64);
        float inv = 1.f / l;
        int t = q0 + quad * 4 + r;
        u16* orow = ob + ((size_t)t * BB + b) * DD + h * DH + n16;
        #pragma unroll
        for (int ot = 0; ot < 4; ot++) orow[ot * 16] = f2b(Oa[ot][r] * inv);
    }
}

// ---------------- host ----------------
extern "C" void kernel_launch(void* const* d_in, const int* in_sizes, int n_in,
                              void* d_out, int out_size, void* d_ws, size_t ws_size,
                              hipStream_t stream) {
    const float* tgt       = (const float*)d_in[0];
    const float* memory    = (const float*)d_in[1];
    const float* queries   = (const float*)d_in[2];
    const float* wk        = (const float*)d_in[3];
    const float* in_proj_w = (const float*)d_in[4];
    const float* in_proj_b = (const float*)d_in[5];
    const float* out_proj_w= (const float*)d_in[6];
    const float* out_proj_b= (const float*)d_in[7];
    const float* lin1_w    = (const float*)d_in[8];
    const float* lin1_b    = (const float*)d_in[9];
    const float* lin2_w    = (const float*)d_in[10];
    const float* lin2_b    = (const float*)d_in[11];
    const float* ln1_g     = (const float*)d_in[12];
    const float* ln1_b     = (const float*)d_in[13];
    const float* ln2_g     = (const float*)d_in[14];
    const float* ln2_b     = (const float*)d_in[15];
    const float* ln3_g     = (const float*)d_in[16];
    const float* ln3_b     = (const float*)d_in[17];

    char* w = (char*)d_ws;
    float* qeff  = (float*)(w + 0);
    float* pbuf  = (float*)(w + 20480);
    float* Acomb = (float*)(w + 675840);
    float* mixed = (float*)(w + 872448);
    u16* y1  = (u16*)(w + 2969600);
    u16* qb  = (u16*)(w + 19746816);
    u16* kvb = (u16*)(w + 36524032);
    u16* ob  = (u16*)(w + 44912640);
    u16* ipwb = (u16*)(w + 44912640);
    u16* memb = (u16*)(w + 46485504);
    u16* opwb = (u16*)(w + 36524032);
    u16* l1wb = (u16*)(w + 37048320);
    u16* l2wb = (u16*)(w + 39145472);
    u16* t1 = qb;
    u16* y2 = ob;
    u16* hb = qb;
    u16* fb = y1;

    // ---- pre-attention conversions (ob region) ----
    cvt_kernel<<<(SS * BB * DD) / 1024, 256, 0, stream>>>(memory, memb);
    cvt_kernel<<<(3 * DD * DD) / 1024, 256, 0, stream>>>(in_proj_w, ipwb);

    // ---- QA block ----
    qeff_kernel<<<1, 512, 0, stream>>>(queries, qeff);
    p_kernel<<<BB * (TT / 4), 256, 0, stream>>>(tgt, qeff, pbuf);
    win_kernel<<<(BB * NW) / 4, 256, 0, stream>>>(pbuf, wk, Acomb);
    mix_kernel<<<BB * NW, 256, 0, stream>>>(Acomb, tgt, mixed);
    ln_qa_kernel<<<(TT * BB) / 4, 256, 0, stream>>>(tgt, mixed, ln1_g, ln1_b, y1);

    // ---- MHA ----
    gemm2<0, 128, 64, 64, 32><<<dim3(DD / 64, (TT * BB) / 128), 256, 0, stream>>>(y1, ipwb, in_proj_b, qb, TT * BB, DD, DD);
    gemm2<0, 128, 64, 64, 32><<<dim3(KVS / 64, (SS * BB) / 128), 256, 0, stream>>>(memb, ipwb + (size_t)DD * DD, in_proj_b + DD, kvb, SS * BB, KVS, DD);
    attn_v3<<<dim3(TT / 64, BB * HH), 256, 0, stream>>>(qb, kvb, ob);
    // kvb dead; convert remaining weights into its region
    cvt_kernel<<<(DD * DD) / 1024, 256, 0, stream>>>(out_proj_w, opwb);
    cvt_kernel<<<(DFF * DD) / 1024, 256, 0, stream>>>(lin1_w, l1wb);
    cvt_kernel<<<(DD * DFF) / 1024, 256, 0, stream>>>(lin2_w, l2wb);
    gemm2<0, 128, 64, 64, 32><<<dim3(DD / 64, (TT * BB) / 128), 256, 0, stream>>>(ob, opwb, out_proj_b, t1, TT * BB, DD, DD);
    ln_rows_kernel<u16><<<(TT * BB) / 4, 256, 0, stream>>>(y1, t1, ln2_g, ln2_b, y2);

    // ---- FFN (4 chunks of 4096 rows; hidden in qb region) ----
    for (int c = 0; c < 4; c++) {
        const u16* y2c = y2 + (size_t)c * 4096 * DD;
        u16* fbc = fb + (size_t)c * 4096 * DD;
        gemm2<1, 128, 64, 64, 32><<<dim3(DFF / 64, 4096 / 128), 256, 0, stream>>>(y2c, l1wb, lin1_b, hb, 4096, DFF, DD);
        gemm2<0, 64, 64, 32, 32><<<dim3(DD / 64, 4096 / 64), 256, 0, stream>>>(hb, l2wb, lin2_b, fbc, 4096, DD, DFF);
    }
    ln_rows_kernel<float><<<(TT * BB) / 4, 256, 0, stream>>>(y2, fb, ln3_g, ln3_b, (float*)d_out);
}